// Round 1
// baseline (126967.017 us; speedup 1.0000x reference)
//
#include <hip/hip_runtime.h>
#include <stdint.h>

typedef unsigned int  u32;
typedef unsigned short u16;

#define SEQ    8192
#define HID    1024
#define NL     5
#define NWG    256
#define TPB    256
#define PAIRS  20                 // (layer,unit) pairs per WG; NWG*PAIRS = NL*HID
#define RPW    20                 // gate-rows per wave (4 waves * 20 = 80 = PAIRS*4)
#define NVR    12                 // rows kept in VGPRs per wave
#define NLR    8                  // rows kept in LDS per wave (NVR+NLR == RPW)
#define WSTEPS (SEQ + NL - 1)     // 8196 wavefront steps
#define LWGS   52                 // producer WGs (= chunks) per layer
#define RING   8                  // slot ring depth (WAR slack = RING-2 steps)
#define CHW    16                 // u32 words per producer chunk (64 B)
#define SSTR   (LWGS * CHW)       // u32 words per (layer, ring-slot) = 832

// ---- workspace layout (bytes) ----
#define WS_X0    ((size_t)0)                        // 8192*512 u32 = 16 MiB (bf16 packed)
#define WS_H5    ((size_t)16*1024*1024)             // 16 MiB
#define WS_SLOT  ((size_t)32*1024*1024)             // 5*8*832 u32 = 130 KiB (pad 192 KiB)
#define WS_SYNC  (WS_SLOT + (size_t)192*1024)       // flags[5][64] u32; dtype flag @+2048
#define WS_NEED  (WS_SYNC + 4096)

// ---------------- helpers ----------------
__device__ __forceinline__ float bf2f(u16 v) { return __uint_as_float(((u32)v) << 16); }
__device__ __forceinline__ float bflo(u32 v) { return __uint_as_float(v << 16); }
__device__ __forceinline__ float bfhi(u32 v) { return __uint_as_float(v & 0xffff0000u); }

__device__ __forceinline__ u16 f2bf(float f) {            // round-to-nearest-even
  u32 u = __float_as_uint(f);
  u32 r = u + 0x7fffu + ((u >> 16) & 1u);
  return (u16)(r >> 16);
}
__device__ __forceinline__ float lrelu(float x) { return (x >= 0.f) ? x : 0.01f * x; }
__device__ __forceinline__ float sigm(float x)  { return 1.f / (1.f + __expf(-x)); }
__device__ __forceinline__ float tanh_f(float x) {
  float e = __expf(-2.f * fabsf(x));
  float t = (1.f - e) / (1.f + e);
  return (x >= 0.f) ? t : -t;
}

// software packed-bf16x2 dot (bit-exact unpack + f32 fma) — proven fallback
__device__ __forceinline__ float dot2bf(u32 w, u32 v, float acc) {
  return fmaf(bfhi(w), bfhi(v), fmaf(bflo(w), bflo(v), acc));
}

// hardware v_dot2_f32_bf16 — validated at runtime by k_detect before use
#if defined(__has_builtin)
#if __has_builtin(__builtin_amdgcn_fdot2_f32_bf16)
#define HAS_DOT2 1
typedef __bf16 bf16x2 __attribute__((ext_vector_type(2)));
__device__ __forceinline__ float hwdot2(u32 a, u32 b, float c) {
  union U { u32 u; bf16x2 v; };
  U x, y; x.u = a; y.u = b;
  return __builtin_amdgcn_fdot2_f32_bf16(x.v, y.v, c, false);
}
#endif
#endif
#ifndef HAS_DOT2
#define HAS_DOT2 0
__device__ __forceinline__ float hwdot2(u32 a, u32 b, float c) { return dot2bf(a, b, c); }
#endif

__device__ __forceinline__ u32 agent_load(const u32* p) {
  return __hip_atomic_load((u32*)p, __ATOMIC_RELAXED, __HIP_MEMORY_SCOPE_AGENT);
}

// LLC-routed single-dword store (fire-and-forget; participates in vmcnt).
__device__ __forceinline__ void llc_store(u32* p, u32 v) {
  asm volatile("global_store_dword %0, %1, off sc0 sc1" : : "v"(p), "v"(v) : "memory");
}

// LLC-routed 16-byte store: [tag | d0 | d1 | d2]. A single-lane naturally
// aligned dwordx4 is one memory transaction, so a consumer that reads
// tag == expected is guaranteed d0..d2 of the SAME group are current.
// This is what lets publishes be fire-and-forget (no vmcnt drain, no
// separate flag store, no release fence) — the tag rides with the data.
typedef u32 u32x4_t __attribute__((ext_vector_type(4)));
__device__ __forceinline__ void llc_store4(u32* p, u32 tag, u32 a, u32 b, u32 c) {
  u32x4_t q; q.x = tag; q.y = a; q.z = b; q.w = c;
  asm volatile("global_store_dwordx4 %0, %1, off sc0 sc1" : : "v"(p), "v"(q) : "memory");
}

__device__ __forceinline__ int first_wg(int l) { return (l << 10) / PAIRS; }  // {0,51,102,153,204}

// chunk geometry: chunk c of layer l is written by WG first_wg(l)+c.
// Pair q (0..9) within a chunk lives at word 1 + q + q/3 (4 groups of
// [tag, up-to-3 pairs]; tags at words 0,4,8,12). Global pair index
// qp = l*512 + (layer-local pair) maps to chunk floor(qp/10), local pair
// qp%10 — and the producer-side mapping (chunk == wg, local pair == lane/2)
// is exact because qp = wg*10 + lane/2 for unit wg*20+lane.

// ---------------- K0: dtype probe + dot2 validation ----------------
__global__ void k_detect(const u32* __restrict__ w1, u32* __restrict__ flag) {
  int lane = threadIdx.x;       // 64 threads
  int cnt = 0;
#pragma unroll
  for (int i = 0; i < 4; ++i) {
    u32 w = w1[lane * 4 + i];
    u32 e = (w >> 23) & 0xffu;
    cnt += (e >= 100u && e <= 140u) ? 1 : 0;
  }
  cnt += __shfl_xor(cnt, 32); cnt += __shfl_xor(cnt, 16); cnt += __shfl_xor(cnt, 8);
  cnt += __shfl_xor(cnt, 4);  cnt += __shfl_xor(cnt, 2);  cnt += __shfl_xor(cnt, 1);
  if (lane == 0) {
    u32 f = (cnt > 128) ? 1u : 0u;
#if HAS_DOT2
    u32 a1 = (u32)f2bf(1.5f)   | ((u32)f2bf(-2.25f) << 16);
    u32 b1v = (u32)f2bf(0.5f)  | ((u32)f2bf(4.0f)   << 16);
    u32 a2 = (u32)f2bf(0.125f) | ((u32)f2bf(3.0f)   << 16);
    u32 b2v = (u32)f2bf(8.0f)  | ((u32)f2bf(-0.5f)  << 16);
    float t1 = hwdot2(a1, b1v, 1.0f);   // 1 + 0.75 - 9   = -7.25
    float t2 = hwdot2(a2, b2v, 0.5f);   // 0.5 + 1 - 1.5  = 0
    if (fabsf(t1 + 7.25f) < 1e-2f && fabsf(t2) < 1e-2f) f |= 2u;
#endif
    *flag = f;
  }
}

// ---------------- K1: X0 = leaky_relu(data_in @ w1.T + b1), stored packed bf16 ----------------
__global__ void __launch_bounds__(256) k_in(const void* __restrict__ din,
                                            const void* __restrict__ w1,
                                            const void* __restrict__ b1,
                                            u32* __restrict__ X0,
                                            const u32* __restrict__ flagp) {
  const u32 isf = *flagp & 1u;
  int t = blockIdx.x, tid = threadIdx.x;
  __shared__ float xs[64];
  if (isf) {
    if (tid < 64) xs[tid] = ((const float*)din)[(size_t)t * 64 + tid];
  } else {
    if (tid < 32) {
      u32 v = ((const u32*)din)[(size_t)t * 32 + tid];
      xs[2 * tid] = bflo(v); xs[2 * tid + 1] = bfhi(v);
    }
  }
  __syncthreads();
  float o[4];
#pragma unroll
  for (int r = 0; r < 4; ++r) {
    int i = tid * 4 + r;
    float a = 0.f;
    if (isf) {
      const float* wr = (const float*)w1 + (size_t)i * 64;
#pragma unroll
      for (int d = 0; d < 64; ++d) a = fmaf(wr[d], xs[d], a);
      a += ((const float*)b1)[i];
    } else {
      const u32* wr = (const u32*)w1 + (size_t)i * 32;
#pragma unroll
      for (int d = 0; d < 32; ++d) {
        u32 w = wr[d];
        a = fmaf(bflo(w), xs[2 * d], a);
        a = fmaf(bfhi(w), xs[2 * d + 1], a);
      }
      a += bf2f(((const u16*)b1)[i]);
    }
    o[r] = lrelu(a);
  }
  X0[(size_t)t * 512 + tid * 2]     = (u32)f2bf(o[0]) | ((u32)f2bf(o[1]) << 16);
  X0[(size_t)t * 512 + tid * 2 + 1] = (u32)f2bf(o[2]) | ((u32)f2bf(o[3]) << 16);
}

// ---------------- K2: persistent wavefront LSTM, tagged-slot push protocol ----------------
// Slots: slots[layer][t mod 8] = 52 chunks x 64 B; each 16 B group is
// [tag=t | 3 h-pairs], published by ONE llc_store4 (fire-and-forget).
// Forward deps (x from layer below, h from own-layer peers) are detected by
// polling the group tags for the exact timestep value — no producer drain,
// no flag store, no min-reduce shuffle chain on the poll path.
// WAR (ring reuse, slack RING-2 = 6 steps) uses lazy fire-and-forget
// progress flags: flags[l][c] = s+2 after step s, checked as f+6 >= s+1.
__global__ void __launch_bounds__(TPB, 1) k_wave(const void* __restrict__ WihP,
                                                 const void* __restrict__ WhhP,
                                                 const void* __restrict__ bihP,
                                                 const void* __restrict__ bhhP,
                                                 const void* __restrict__ h0P,
                                                 const void* __restrict__ c0P,
                                                 const u32* __restrict__ X0,
                                                 u32* __restrict__ H5,
                                                 u32* slots, u32* flags,
                                                 const u32* __restrict__ flagp) {
  const u32 dfl = *flagp;
  const u32 isf = dfl & 1u;
  const bool ud2 = (dfl & 2u) != 0u;
  const int tid  = threadIdx.x;
  const int lane = tid & 63;
  const int wv   = tid >> 6;
  const int wg   = blockIdx.x;

  __shared__ u32   vlds[2][64 * 17];            // [layer-sel][lane*17 + d] (odd stride: conflict-free)
  __shared__ u32   wlds[4 * NLR * 1024];        // [wave][row][d4][lane][4] 128 KiB, b128-friendly
  __shared__ float zrow[80];

  // ---- load weights: rows 0..NVR-1 -> VGPRs, rows NVR..19 -> LDS ----
  u32 W[NVR][16];
#pragma unroll
  for (int i = 0; i < RPW; ++i) {
    int rr = wv * RPW + i;
    int p = rr >> 2, q = rr & 3;
    int g = wg * PAIRS + p;
    int lg = g >> 10, j = g & 1023;
    u32 tmp[16];
    if (isf) {
      const float* matf = (lane < 32) ? (const float*)WihP : (const float*)WhhP;
      const float4* s4 = (const float4*)(matf + ((size_t)(lg * 4096 + q * 1024 + j)) * 1024 + (lane & 31) * 32);
#pragma unroll
      for (int q4 = 0; q4 < 8; ++q4) {
        float4 f = s4[q4];
        tmp[q4 * 2]     = (u32)f2bf(f.x) | ((u32)f2bf(f.y) << 16);
        tmp[q4 * 2 + 1] = (u32)f2bf(f.z) | ((u32)f2bf(f.w) << 16);
      }
    } else {
      const u32* mat = (lane < 32) ? (const u32*)WihP : (const u32*)WhhP;
      const uint4* s4 = (const uint4*)(mat + ((size_t)(lg * 4096 + q * 1024 + j)) * 512 + (lane & 31) * 16);
      uint4 a0 = s4[0], a1 = s4[1], a2 = s4[2], a3 = s4[3];
      tmp[0]=a0.x; tmp[1]=a0.y; tmp[2]=a0.z;  tmp[3]=a0.w;
      tmp[4]=a1.x; tmp[5]=a1.y; tmp[6]=a1.z;  tmp[7]=a1.w;
      tmp[8]=a2.x; tmp[9]=a2.y; tmp[10]=a2.z; tmp[11]=a2.w;
      tmp[12]=a3.x;tmp[13]=a3.y;tmp[14]=a3.z; tmp[15]=a3.w;
    }
    if (i < NVR) {
#pragma unroll
      for (int d = 0; d < 16; ++d) W[i][d] = tmp[d];
    } else {
      u32* base = &wlds[(wv * NLR + (i - NVR)) * 1024];
#pragma unroll
      for (int d4 = 0; d4 < 4; ++d4) {
        uint4 v4 = make_uint4(tmp[d4*4], tmp[d4*4+1], tmp[d4*4+2], tmp[d4*4+3]);
        *(uint4*)&base[d4 * 256 + lane * 4] = v4;
      }
    }
  }

  // ---- per-unit state in wave0 registers (lane < PAIRS owns one unit) ----
  float cst = 0.f;
  float b0 = 0.f, b1g = 0.f, b2g = 0.f, b3g = 0.f;
  if (wv == 0 && lane < PAIRS) {
    int g = wg * PAIRS + lane, lg = g >> 10, j = g & 1023;
    cst = isf ? ((const float*)c0P)[lg * 1024 + j] : bf2f(((const u16*)c0P)[lg * 1024 + j]);
#pragma unroll
    for (int q = 0; q < 4; ++q) {
      int r = lg * 4096 + q * 1024 + j;
      float bb = isf ? (((const float*)bihP)[r] + ((const float*)bhhP)[r])
                     : (bf2f(((const u16*)bihP)[r]) + bf2f(((const u16*)bhhP)[r]));
      if (q == 0) b0 = bb; else if (q == 1) b1g = bb; else if (q == 2) b2g = bb; else b3g = bb;
    }
  }

  const int l_lo = (wg * PAIRS) >> 10;
  const int l_hi = (wg * PAIRS + PAIRS - 1) >> 10;
  const bool span = (l_hi != l_lo);
  const int f_lo = first_wg(l_lo), f_hi = first_wg(l_hi);
  const int c_lo = wg - f_lo, c_hi = wg - f_hi;

  // ---- h0 -> ring slot 7 (t = -1), tag = 0xFFFFFFFF, tagged-group stores ----
  if (wv == 0) {
    int g = wg * PAIRS + lane;
    int lg = g >> 10, j = g & 1023;
    u32 hv = 0;
    if ((lane < PAIRS) && !(lane & 1)) {
      if (isf) {
        const float* h0f = (const float*)h0P;
        hv = (u32)f2bf(h0f[lg * 1024 + j]) | ((u32)f2bf(h0f[lg * 1024 + j + 1]) << 16);
      } else {
        const u16* h0b = (const u16*)h0P;
        hv = (u32)h0b[lg * 1024 + j] | ((u32)h0b[lg * 1024 + j + 1] << 16);
      }
    }
    u32 ga = (u32)__shfl((int)hv, 6 * (lane & 3));
    u32 gb = (u32)__shfl((int)hv, 6 * (lane & 3) + 2);
    u32 gc = (u32)__shfl((int)hv, 6 * (lane & 3) + 4);
#pragma unroll
    for (int sel = 0; sel < 2; ++sel) {
      int L = l_lo + sel;
      if (L <= l_hi) {
        int cc = (sel == 0) ? c_lo : c_hi;
        u32* cb = slots + (L * RING + 7) * SSTR + cc * CHW;
        if (lane < 4) llc_store4(cb + lane * 4, 0xFFFFFFFFu, ga, gb, gc);
      }
    }
  }
  __syncthreads();                              // weights in LDS + init issued

  int budget = 20000000;                        // bounded polling: never hard-hang

  for (int s = 0; s < WSTEPS; ++s) {
    const int t0 = s - l_lo;
    const int t1 = s - l_hi;
    if (t1 >= SEQ) break;                       // all owned layers finished
    const bool p0 = (t0 >= 0) && (t0 < SEQ);
    const bool p1 = span && (t1 >= 0);          // t1 < SEQ by the break above

    // ---- wave0: poll group tags (forward deps) + WAR progress flags ----
    if (wv == 0) {
      const u32 need = (u32)(s + 1);
      const int lc = lane * CHW;
      const u32 *tA = 0, *tXA = 0, *tB = 0, *tXB = 0, *wf1 = 0, *wf2 = 0;
      u32 eA = 0, eXA = 0, eB = 0, eXB = 0;
      if (p0) { tA = slots + (l_lo * RING + ((t0 - 1) & 7)) * SSTR + lc; eA = (u32)(t0 - 1); }
      if (p0 && l_lo > 0) { tXA = slots + ((l_lo - 1) * RING + (t0 & 7)) * SSTR + lc; eXA = (u32)t0; }
      if (p1) {
        tB  = slots + (l_hi * RING + ((t1 - 1) & 7)) * SSTR + lc; eB  = (u32)(t1 - 1);
        tXB = slots + (l_lo * RING + (t1 & 7)) * SSTR + lc;       eXB = (u32)t1;
      }
      if (p0 && (l_lo + 1) < NL)         wf1 = flags + (l_lo + 1) * 64 + lane;
      if (span && p1 && (l_hi + 1) < NL) wf2 = flags + (l_hi + 1) * 64 + lane;
      for (;;) {
        bool pass = true;
        if (lane < LWGS) {
          if (tA)  pass = pass & (agent_load(tA)  == eA)  & (agent_load(tA + 4)  == eA)
                               & (agent_load(tA + 8)  == eA)  & (agent_load(tA + 12)  == eA);
          if (tXA) pass = pass & (agent_load(tXA) == eXA) & (agent_load(tXA + 4) == eXA)
                               & (agent_load(tXA + 8) == eXA) & (agent_load(tXA + 12) == eXA);
          if (tB)  pass = pass & (agent_load(tB)  == eB)  & (agent_load(tB + 4)  == eB)
                               & (agent_load(tB + 8)  == eB)  & (agent_load(tB + 12)  == eB);
          if (tXB) pass = pass & (agent_load(tXB) == eXB) & (agent_load(tXB + 4) == eXB)
                               & (agent_load(tXB + 8) == eXB) & (agent_load(tXB + 12) == eXB);
          if (wf1) pass = pass & ((agent_load(wf1) + (u32)(RING - 2)) >= need);
          if (wf2) pass = pass & ((agent_load(wf2) + (u32)(RING - 2)) >= need);
        }
        if (__all(pass)) break;
        if (--budget < 0) break;
      }
    }
    __syncthreads();            // A: tags observed -> data is at the LLC

    // ---- stage v = [x || h] per owned layer from tagged chunks -> LDS ----
#pragma unroll
    for (int sel = 0; sel < 2; ++sel) {
      int L = l_lo + sel;
      if (L <= l_hi) {
        int t = s - L;
        if (t >= 0 && t < SEQ) {
#pragma unroll
          for (int rr2 = 0; rr2 < 4; ++rr2) {
            int gidx = tid + rr2 * 256;
            u32 val;
            if (gidx < 512) {                    // x pair
              if (L == 0) {
                val = X0[(size_t)t * 512 + gidx];
              } else {
                int qp = (L - 1) * 512 + gidx;
                int wsrc = (qp * 6554) >> 16;    // qp / 10 (exact for qp < 16384)
                int qq = qp - wsrc * 10;
                int word = 1 + qq + ((qq * 11) >> 5);  // + qq/3 (group tag skip)
                val = agent_load(slots + ((L - 1) * RING + (t & 7)) * SSTR
                                 + (wsrc - first_wg(L - 1)) * CHW + word);
              }
            } else {                             // h pair
              int qp = L * 512 + (gidx - 512);
              int wsrc = (qp * 6554) >> 16;
              int qq = qp - wsrc * 10;
              int word = 1 + qq + ((qq * 11) >> 5);
              val = agent_load(slots + (L * RING + ((t - 1) & 7)) * SSTR
                               + (wsrc - first_wg(L)) * CHW + word);
            }
            vlds[sel][(gidx >> 4) * 17 + (gidx & 15)] = val;
          }
        }
      }
    }
    __syncthreads();            // B: vlds ready

    // ---- 20 row dots per wave (12 VGPR rows + 8 LDS rows) ----
    {
      int curl = -1;
      u32 vreg[16];
#pragma unroll
      for (int i = 0; i < RPW; ++i) {
        int rr = wv * RPW + i;
        int p = rr >> 2;
        int g = wg * PAIRS + p;
        int lg = g >> 10;
        int t = s - lg;
        if (t >= 0 && t < SEQ) {
          if (lg != curl) {
            curl = lg;
            const u32* vb = &vlds[lg - l_lo][lane * 17];
#pragma unroll
            for (int d = 0; d < 16; ++d) vreg[d] = vb[d];
          }
          float a0 = 0.f, a1 = 0.f, a2 = 0.f, a3 = 0.f;
          if (i < NVR) {
            if (ud2) {
#pragma unroll
              for (int d = 0; d < 16; d += 4) {
                a0 = hwdot2(W[i][d],   vreg[d],   a0);
                a1 = hwdot2(W[i][d+1], vreg[d+1], a1);
                a2 = hwdot2(W[i][d+2], vreg[d+2], a2);
                a3 = hwdot2(W[i][d+3], vreg[d+3], a3);
              }
            } else {
#pragma unroll
              for (int d = 0; d < 16; d += 4) {
                a0 = fmaf(bflo(W[i][d]),   bflo(vreg[d]),   a0);
                a0 = fmaf(bfhi(W[i][d]),   bfhi(vreg[d]),   a0);
                a1 = fmaf(bflo(W[i][d+1]), bflo(vreg[d+1]), a1);
                a1 = fmaf(bfhi(W[i][d+1]), bfhi(vreg[d+1]), a1);
                a2 = fmaf(bflo(W[i][d+2]), bflo(vreg[d+2]), a2);
                a2 = fmaf(bfhi(W[i][d+2]), bfhi(vreg[d+2]), a2);
                a3 = fmaf(bflo(W[i][d+3]), bflo(vreg[d+3]), a3);
                a3 = fmaf(bfhi(W[i][d+3]), bfhi(vreg[d+3]), a3);
              }
            }
          } else {
            const uint4* wl = (const uint4*)&wlds[(wv * NLR + (i - NVR)) * 1024 + lane * 4];
#pragma unroll
            for (int d4 = 0; d4 < 4; ++d4) {
              uint4 w4 = wl[d4 * 64];
              if (ud2) {
                a0 = hwdot2(w4.x, vreg[d4*4+0], a0);
                a1 = hwdot2(w4.y, vreg[d4*4+1], a1);
                a2 = hwdot2(w4.z, vreg[d4*4+2], a2);
                a3 = hwdot2(w4.w, vreg[d4*4+3], a3);
              } else {
                a0 = fmaf(bflo(w4.x), bflo(vreg[d4*4+0]), a0);
                a0 = fmaf(bfhi(w4.x), bfhi(vreg[d4*4+0]), a0);
                a1 = fmaf(bflo(w4.y), bflo(vreg[d4*4+1]), a1);
                a1 = fmaf(bfhi(w4.y), bfhi(vreg[d4*4+1]), a1);
                a2 = fmaf(bflo(w4.z), bflo(vreg[d4*4+2]), a2);
                a2 = fmaf(bfhi(w4.z), bfhi(vreg[d4*4+2]), a2);
                a3 = fmaf(bflo(w4.w), bflo(vreg[d4*4+3]), a3);
                a3 = fmaf(bfhi(w4.w), bfhi(vreg[d4*4+3]), a3);
              }
            }
          }
          float r = (a0 + a1) + (a2 + a3);
          r += __shfl_xor(r, 32);
          r += __shfl_xor(r, 16);
          r += __shfl_xor(r, 8);
          r += __shfl_xor(r, 4);
          r += __shfl_xor(r, 2);
          r += __shfl_xor(r, 1);
          if (lane == 0) zrow[rr] = r;
        }
      }
    }
    __syncthreads();            // C: zrow ready

    // ---- wave0: gates + cell update + tagged publish (fire-and-forget) ----
    if (wv == 0) {
      u16 hb = 0;
      int g = wg * PAIRS + lane;     // valid for lane < PAIRS
      int lg = g >> 10;
      int tg = s - lg;
      bool act = (lane < PAIRS) && (tg >= 0) && (tg < SEQ);
      if (act) {
        float zi = zrow[lane * 4 + 0] + b0;
        float zf = zrow[lane * 4 + 1] + b1g;
        float zg = zrow[lane * 4 + 2] + b2g;
        float zo = zrow[lane * 4 + 3] + b3g;
        float ig = sigm(zi), fg = sigm(zf), gg = tanh_f(zg), og = sigm(zo);
        float c = fg * cst + ig * gg;
        cst = c;
        hb = f2bf(og * tanh_f(c));
      }
      u16 hnb = (u16)__shfl_xor((int)hb, 1);
      u32 v = (u32)hb | ((u32)hnb << 16);        // even lanes hold the pair
      // gather group payloads: group k = pairs 3k..3k+2 = lanes 6k,6k+2,6k+4
      u32 ga = (u32)__shfl((int)v, 6 * (lane & 3));
      u32 gb = (u32)__shfl((int)v, 6 * (lane & 3) + 2);
      u32 gc = (u32)__shfl((int)v, 6 * (lane & 3) + 4);
#pragma unroll
      for (int sel = 0; sel < 2; ++sel) {
        int L = l_lo + sel;
        if (L <= l_hi) {
          int tL = s - L;
          if (tL >= 0 && tL < SEQ) {
            int cc = (sel == 0) ? c_lo : c_hi;
            u32* cb = slots + (L * RING + (tL & 7)) * SSTR + cc * CHW;
            if (lane < 4) llc_store4(cb + lane * 4, (u32)tL, ga, gb, gc);
            if (act && !(lane & 1) && (lg == L) && (L == NL - 1))
              H5[(size_t)tL * 512 + ((g & 1023) >> 1)] = v;
          }
        }
      }
      // WAR progress flags (lazy, 6-step slack; only layers >= 1 are read)
      if (lane == 0) {
        if (l_lo > 0) llc_store(flags + l_lo * 64 + c_lo, (u32)(s + 2));
        if (span)     llc_store(flags + l_hi * 64 + c_hi, (u32)(s + 2));
      }
    }
  }
}

// ---------------- K3: out = tanh(leaky_relu(h5) @ w2.T + b2) ----------------
__global__ void __launch_bounds__(256) k_out(const u32* __restrict__ H5,
                                             const void* __restrict__ w2,
                                             const void* __restrict__ b2,
                                             void* __restrict__ out,
                                             const u32* __restrict__ flagp) {
  const u32 isf = *flagp & 1u;
  int t = blockIdx.x, tid = threadIdx.x;
  __shared__ float hs[1024];
  __shared__ float part[256];
#pragma unroll
  for (int r = 0; r < 2; ++r) {
    int idx = tid + r * 256;
    u32 v = H5[(size_t)t * 512 + idx];
    hs[2 * idx]     = lrelu(bflo(v));
    hs[2 * idx + 1] = lrelu(bfhi(v));
  }
  __syncthreads();
  int n = tid & 63, qq = tid >> 6;
  float a = 0.f;
  if (isf) {
    const float* wr = (const float*)w2 + (size_t)n * 1024 + qq * 256;
    const float* hb = &hs[qq * 256];
#pragma unroll
    for (int d = 0; d < 256; ++d) a = fmaf(wr[d], hb[d], a);
  } else {
    const u32* wr = (const u32*)w2 + (size_t)n * 512 + qq * 128;
    const float* hb = &hs[qq * 256];
#pragma unroll
    for (int d = 0; d < 128; ++d) {
      u32 w = wr[d];
      a = fmaf(bflo(w), hb[2 * d], a);
      a = fmaf(bfhi(w), hb[2 * d + 1], a);
    }
  }
  part[tid] = a;
  __syncthreads();
  if (tid < 64) {
    float bb = isf ? ((const float*)b2)[tid] : bf2f(((const u16*)b2)[tid]);
    float y = part[tid] + part[tid + 64] + part[tid + 128] + part[tid + 192] + bb;
    float r = tanh_f(y);
    if (isf) ((float*)out)[(size_t)t * 64 + tid] = r;
    else     ((u16*)out)[(size_t)t * 64 + tid] = f2bf(r);
  }
}

// ---------------- launcher ----------------
extern "C" void kernel_launch(void* const* d_in, const int* in_sizes, int n_in,
                              void* d_out, int out_size, void* d_ws, size_t ws_size,
                              hipStream_t stream) {
  (void)in_sizes; (void)n_in; (void)out_size;
  if (ws_size < WS_NEED) return;

  const void* din = d_in[0];
  const void* w1  = d_in[1];
  const void* b1  = d_in[2];
  const void* Wih = d_in[3];
  const void* Whh = d_in[4];
  const void* bih = d_in[5];
  const void* bhh = d_in[6];
  const void* w2  = d_in[7];
  const void* b2  = d_in[8];
  const void* h0  = d_in[9];
  const void* c0  = d_in[10];

  char* ws = (char*)d_ws;
  u32* X0    = (u32*)(ws + WS_X0);
  u32* H5    = (u32*)(ws + WS_H5);
  u32* slot  = (u32*)(ws + WS_SLOT);
  u32* flags = (u32*)(ws + WS_SYNC);
  u32* dflag = (u32*)(ws + WS_SYNC + 2048);

  hipMemsetAsync(flags, 0, 4096, stream);      // zero flags + dtype word (ws poisoned 0xAA)
  k_detect<<<1, 64, 0, stream>>>((const u32*)w1, dflag);
  k_in  <<<SEQ, 256, 0, stream>>>(din, w1, b1, X0, dflag);
  k_wave<<<NWG, TPB, 0, stream>>>(Wih, Whh, bih, bhh, h0, c0, X0, H5, slot, flags, dflag);
  k_out <<<SEQ, 256, 0, stream>>>(H5, w2, b2, d_out, dflag);
}

// Round 2
// 120361.865 us; speedup vs baseline: 1.0549x; 1.0549x over previous
//
#include <hip/hip_runtime.h>
#include <stdint.h>

typedef unsigned int  u32;
typedef unsigned short u16;

#define SEQ    8192
#define HID    1024
#define NL     5
#define NWG    256
#define TPB    256
#define PAIRS  20                 // (layer,unit) pairs per WG; NWG*PAIRS = NL*HID
#define RPW    20                 // gate-rows per wave (4 waves * 20 = 80 = PAIRS*4)
#define NVR    12                 // rows kept in VGPRs per wave
#define NLR    8                  // rows kept in LDS per wave (NVR+NLR == RPW)
#define WSTEPS (SEQ + NL - 1)     // 8196 wavefront steps
#define LWGS   52                 // producer WGs per layer
#define RING   8                  // slot ring depth (WAR slack = RING-2 steps)

// ---- workspace layout (bytes) ----
#define WS_X0    ((size_t)0)                        // 8192*512 u32 = 16 MiB (bf16 packed)
#define WS_H5    ((size_t)16*1024*1024)             // 16 MiB
#define WS_SLOT  ((size_t)32*1024*1024)             // 5*8*512 u32 = 80 KiB (pad 128 KiB)
#define WS_SYNC  (WS_SLOT + (size_t)128*1024)       // flags[5][64] u32; dtype flag @+2048
#define WS_NEED  (WS_SYNC + 4096)

// ---------------- helpers ----------------
__device__ __forceinline__ float bf2f(u16 v) { return __uint_as_float(((u32)v) << 16); }
__device__ __forceinline__ float bflo(u32 v) { return __uint_as_float(v << 16); }
__device__ __forceinline__ float bfhi(u32 v) { return __uint_as_float(v & 0xffff0000u); }

__device__ __forceinline__ u16 f2bf(float f) {            // round-to-nearest-even
  u32 u = __float_as_uint(f);
  u32 r = u + 0x7fffu + ((u >> 16) & 1u);
  return (u16)(r >> 16);
}
__device__ __forceinline__ float lrelu(float x) { return (x >= 0.f) ? x : 0.01f * x; }
__device__ __forceinline__ float sigm(float x)  { return 1.f / (1.f + __expf(-x)); }
__device__ __forceinline__ float tanh_f(float x) {
  float e = __expf(-2.f * fabsf(x));
  float t = (1.f - e) / (1.f + e);
  return (x >= 0.f) ? t : -t;
}

// software packed-bf16x2 dot (bit-exact unpack + f32 fma) — proven fallback
__device__ __forceinline__ float dot2bf(u32 w, u32 v, float acc) {
  return fmaf(bfhi(w), bfhi(v), fmaf(bflo(w), bflo(v), acc));
}

// hardware v_dot2_f32_bf16 — validated at runtime by k_detect before use
#if defined(__has_builtin)
#if __has_builtin(__builtin_amdgcn_fdot2_f32_bf16)
#define HAS_DOT2 1
typedef __bf16 bf16x2 __attribute__((ext_vector_type(2)));
__device__ __forceinline__ float hwdot2(u32 a, u32 b, float c) {
  union U { u32 u; bf16x2 v; };
  U x, y; x.u = a; y.u = b;
  return __builtin_amdgcn_fdot2_f32_bf16(x.v, y.v, c, false);
}
#endif
#endif
#ifndef HAS_DOT2
#define HAS_DOT2 0
__device__ __forceinline__ float hwdot2(u32 a, u32 b, float c) { return dot2bf(a, b, c); }
#endif

__device__ __forceinline__ u32 agent_load(const u32* p) {
  return __hip_atomic_load((u32*)p, __ATOMIC_RELAXED, __HIP_MEMORY_SCOPE_AGENT);
}
__device__ __forceinline__ void agent_store(u32* p, u32 v) {
  __hip_atomic_store(p, v, __ATOMIC_RELAXED, __HIP_MEMORY_SCOPE_AGENT);
}

// Release ordering for LLC-routed (sc1 atomic) stores WITHOUT the agent-fence
// L2 writeback/invalidate: vmcnt(0) means all prior sc1 stores have reached the
// LLC coherence point; a subsequent flag store is then globally ordered after
// them. "memory" clobber pins compiler ordering.
__device__ __forceinline__ void rel_drain() {
  asm volatile("s_waitcnt vmcnt(0)" ::: "memory");
}

__device__ __forceinline__ int first_wg(int l) { return (l << 10) / PAIRS; }  // {0,51,102,153,204}

// ---------------- K0: dtype probe + dot2 validation ----------------
__global__ void k_detect(const u32* __restrict__ w1, u32* __restrict__ flag) {
  int lane = threadIdx.x;       // 64 threads
  int cnt = 0;
#pragma unroll
  for (int i = 0; i < 4; ++i) {
    u32 w = w1[lane * 4 + i];
    u32 e = (w >> 23) & 0xffu;
    cnt += (e >= 100u && e <= 140u) ? 1 : 0;
  }
  cnt += __shfl_xor(cnt, 32); cnt += __shfl_xor(cnt, 16); cnt += __shfl_xor(cnt, 8);
  cnt += __shfl_xor(cnt, 4);  cnt += __shfl_xor(cnt, 2);  cnt += __shfl_xor(cnt, 1);
  if (lane == 0) {
    u32 f = (cnt > 128) ? 1u : 0u;
#if HAS_DOT2
    u32 a1 = (u32)f2bf(1.5f)   | ((u32)f2bf(-2.25f) << 16);
    u32 b1v = (u32)f2bf(0.5f)  | ((u32)f2bf(4.0f)   << 16);
    u32 a2 = (u32)f2bf(0.125f) | ((u32)f2bf(3.0f)   << 16);
    u32 b2v = (u32)f2bf(8.0f)  | ((u32)f2bf(-0.5f)  << 16);
    float t1 = hwdot2(a1, b1v, 1.0f);   // 1 + 0.75 - 9   = -7.25
    float t2 = hwdot2(a2, b2v, 0.5f);   // 0.5 + 1 - 1.5  = 0
    if (fabsf(t1 + 7.25f) < 1e-2f && fabsf(t2) < 1e-2f) f |= 2u;
#endif
    *flag = f;
  }
}

// ---------------- K1: X0 = leaky_relu(data_in @ w1.T + b1), stored packed bf16 ----------------
__global__ void __launch_bounds__(256) k_in(const void* __restrict__ din,
                                            const void* __restrict__ w1,
                                            const void* __restrict__ b1,
                                            u32* __restrict__ X0,
                                            const u32* __restrict__ flagp) {
  const u32 isf = *flagp & 1u;
  int t = blockIdx.x, tid = threadIdx.x;
  __shared__ float xs[64];
  if (isf) {
    if (tid < 64) xs[tid] = ((const float*)din)[(size_t)t * 64 + tid];
  } else {
    if (tid < 32) {
      u32 v = ((const u32*)din)[(size_t)t * 32 + tid];
      xs[2 * tid] = bflo(v); xs[2 * tid + 1] = bfhi(v);
    }
  }
  __syncthreads();
  float o[4];
#pragma unroll
  for (int r = 0; r < 4; ++r) {
    int i = tid * 4 + r;
    float a = 0.f;
    if (isf) {
      const float* wr = (const float*)w1 + (size_t)i * 64;
#pragma unroll
      for (int d = 0; d < 64; ++d) a = fmaf(wr[d], xs[d], a);
      a += ((const float*)b1)[i];
    } else {
      const u32* wr = (const u32*)w1 + (size_t)i * 32;
#pragma unroll
      for (int d = 0; d < 32; ++d) {
        u32 w = wr[d];
        a = fmaf(bflo(w), xs[2 * d], a);
        a = fmaf(bfhi(w), xs[2 * d + 1], a);
      }
      a += bf2f(((const u16*)b1)[i]);
    }
    o[r] = lrelu(a);
  }
  X0[(size_t)t * 512 + tid * 2]     = (u32)f2bf(o[0]) | ((u32)f2bf(o[1]) << 16);
  X0[(size_t)t * 512 + tid * 2 + 1] = (u32)f2bf(o[2]) | ((u32)f2bf(o[3]) << 16);
}

// ---------------- K2: persistent wavefront LSTM ----------------
// R0 flag protocol (proven at 112.9 ms), with three critical-path edits:
//  (a) the dependency poll runs on WAVE1 (idle between barriers C and A),
//      overlapping wave0's publish drain (~1 LLC RT removed per step);
//  (b) poll uses per-lane sticky booleans + one __all() ballot instead of a
//      6-deep __shfl_xor min-reduce chain per iteration;
//  (c) after 4 failed iterations the poller s_sleep(1)s, cutting spin load
//      pressure on the hot flag lines (straggler mode only).
// Flags: after completing step s, WG stores s+2 into its word of each owned
// layer. Wait before step s: fwd flags (layers mlo..l_hi) >= s+1 and WAR flag
// (l_hi+1) + RING-2 >= s+1. Release ordering = vmcnt drain before flag store.
__global__ void __launch_bounds__(TPB, 1) k_wave(const void* __restrict__ WihP,
                                                 const void* __restrict__ WhhP,
                                                 const void* __restrict__ bihP,
                                                 const void* __restrict__ bhhP,
                                                 const void* __restrict__ h0P,
                                                 const void* __restrict__ c0P,
                                                 const u32* __restrict__ X0,
                                                 u32* __restrict__ H5,
                                                 u32* slots, u32* flags,
                                                 const u32* __restrict__ flagp) {
  const u32 dfl = *flagp;
  const u32 isf = dfl & 1u;
  const bool ud2 = (dfl & 2u) != 0u;
  const int tid  = threadIdx.x;
  const int lane = tid & 63;
  const int wv   = tid >> 6;
  const int wg   = blockIdx.x;

  __shared__ u32   vlds[2][64 * 17];            // [layer-sel][lane*17 + d] (odd stride: conflict-free)
  __shared__ u32   wlds[4 * NLR * 1024];        // [wave][row][d4][lane][4] 128 KiB, b128-friendly
  __shared__ float zrow[80];

  // ---- load weights: rows 0..NVR-1 -> VGPRs, rows NVR..19 -> LDS ----
  u32 W[NVR][16];
#pragma unroll
  for (int i = 0; i < RPW; ++i) {
    int rr = wv * RPW + i;
    int p = rr >> 2, q = rr & 3;
    int g = wg * PAIRS + p;
    int lg = g >> 10, j = g & 1023;
    u32 tmp[16];
    if (isf) {
      const float* matf = (lane < 32) ? (const float*)WihP : (const float*)WhhP;
      const float4* s4 = (const float4*)(matf + ((size_t)(lg * 4096 + q * 1024 + j)) * 1024 + (lane & 31) * 32);
#pragma unroll
      for (int q4 = 0; q4 < 8; ++q4) {
        float4 f = s4[q4];
        tmp[q4 * 2]     = (u32)f2bf(f.x) | ((u32)f2bf(f.y) << 16);
        tmp[q4 * 2 + 1] = (u32)f2bf(f.z) | ((u32)f2bf(f.w) << 16);
      }
    } else {
      const u32* mat = (lane < 32) ? (const u32*)WihP : (const u32*)WhhP;
      const uint4* s4 = (const uint4*)(mat + ((size_t)(lg * 4096 + q * 1024 + j)) * 512 + (lane & 31) * 16);
      uint4 a0 = s4[0], a1 = s4[1], a2 = s4[2], a3 = s4[3];
      tmp[0]=a0.x; tmp[1]=a0.y; tmp[2]=a0.z;  tmp[3]=a0.w;
      tmp[4]=a1.x; tmp[5]=a1.y; tmp[6]=a1.z;  tmp[7]=a1.w;
      tmp[8]=a2.x; tmp[9]=a2.y; tmp[10]=a2.z; tmp[11]=a2.w;
      tmp[12]=a3.x;tmp[13]=a3.y;tmp[14]=a3.z; tmp[15]=a3.w;
    }
    if (i < NVR) {
#pragma unroll
      for (int d = 0; d < 16; ++d) W[i][d] = tmp[d];
    } else {
      u32* base = &wlds[(wv * NLR + (i - NVR)) * 1024];
#pragma unroll
      for (int d4 = 0; d4 < 4; ++d4) {
        uint4 v4 = make_uint4(tmp[d4*4], tmp[d4*4+1], tmp[d4*4+2], tmp[d4*4+3]);
        *(uint4*)&base[d4 * 256 + lane * 4] = v4;
      }
    }
  }

  // ---- per-unit state in wave0 registers (lane < PAIRS owns one unit) ----
  float cst = 0.f;
  float b0 = 0.f, b1g = 0.f, b2g = 0.f, b3g = 0.f;
  if (wv == 0 && lane < PAIRS) {
    int g = wg * PAIRS + lane, lg = g >> 10, j = g & 1023;
    cst = isf ? ((const float*)c0P)[lg * 1024 + j] : bf2f(((const u16*)c0P)[lg * 1024 + j]);
#pragma unroll
    for (int q = 0; q < 4; ++q) {
      int r = lg * 4096 + q * 1024 + j;
      float bb = isf ? (((const float*)bihP)[r] + ((const float*)bhhP)[r])
                     : (bf2f(((const u16*)bihP)[r]) + bf2f(((const u16*)bhhP)[r]));
      if (q == 0) b0 = bb; else if (q == 1) b1g = bb; else if (q == 2) b2g = bb; else b3g = bb;
    }
  }
  if (tid < PAIRS / 2) {          // h0 -> ring slot 7 (t = -1)
    int g = wg * PAIRS + 2 * tid, lg = g >> 10, j = g & 1023;
    u32 v;
    if (isf) {
      const float* h0f = (const float*)h0P;
      v = (u32)f2bf(h0f[lg * 1024 + j]) | ((u32)f2bf(h0f[lg * 1024 + j + 1]) << 16);
    } else {
      const u16* h0b = (const u16*)h0P;
      v = (u32)h0b[lg * 1024 + j] | ((u32)h0b[lg * 1024 + j + 1] << 16);
    }
    agent_store(&slots[(size_t)(lg * RING + 7) * 512 + (j >> 1)], v);
  }

  const int l_lo = (wg * PAIRS) >> 10;
  const int l_hi = (wg * PAIRS + PAIRS - 1) >> 10;
  const int mlo = (l_lo > 0) ? l_lo - 1 : 0;
  const bool haswar = (l_hi + 1) < NL;
  const int f_lo = first_wg(l_lo), f_hi = first_wg(l_hi);
  // fwd flag arrays to poll: layers mlo, mlo+1 (if <= l_hi), mlo+2 (if <= l_hi)
  const bool hasB = (mlo + 1) <= l_hi;
  const bool hasC = (mlo + 2) <= l_hi;

  __threadfence();                              // once: full fence before first flag
  __syncthreads();
  if (tid == 0) {                               // init done: flag = 1
    agent_store(&flags[l_lo * 64 + (wg - f_lo)], 1u);
    if (l_hi != l_lo) agent_store(&flags[l_hi * 64 + (wg - f_hi)], 1u);
  }

  int budget = 20000000;                        // bounded polling: never hard-hang

  for (int s = 0; s < WSTEPS; ++s) {
    // ---- wave1: wait on deps (overlaps wave0's publish drain of step s-1) ----
    if (wv == 1) {
      const u32 need = (u32)(s + 1);
      const bool active = (lane < LWGS);
      // sticky satisfied bits: flags are monotone, so once a condition holds
      // it stays held — stop reloading it (cuts steady-state poll traffic).
      bool okA = !active;
      bool okB = !active || !hasB;
      bool okC = !active || !hasC;
      bool okW = !active || !haswar;
      int misses = 0;
      for (;;) {
        if (!okA) okA = agent_load(&flags[mlo * 64 + lane]) >= need;
        if (!okB) okB = agent_load(&flags[(mlo + 1) * 64 + lane]) >= need;
        if (!okC) okC = agent_load(&flags[(mlo + 2) * 64 + lane]) >= need;
        if (!okW) okW = (agent_load(&flags[(l_hi + 1) * 64 + lane]) + (u32)(RING - 2)) >= need;
        if (__all(okA && okB && okC && okW)) break;
        if (--budget < 0) break;
        if (++misses >= 4) __builtin_amdgcn_s_sleep(1);   // straggler mode: back off
      }
    }
    __syncthreads();            // A: deps satisfied for whole block

    // ---- stage v = [x || h] per owned layer (coalesced LLC loads -> LDS) ----
#pragma unroll
    for (int sel = 0; sel < 2; ++sel) {
      int L = l_lo + sel;
      if (L <= l_hi) {
        int t = s - L;
        if (t >= 0 && t < SEQ) {
          const u32* hsrc = slots + (size_t)(L * RING + ((t - 1) & 7)) * 512;
          const u32* xsrc = (L == 0) ? (X0 + (size_t)t * 512)
                                     : (slots + (size_t)((L - 1) * RING + (t & 7)) * 512);
#pragma unroll
          for (int rr2 = 0; rr2 < 4; ++rr2) {
            int gidx = tid + rr2 * 256;
            u32 val;
            if (gidx < 512) val = (L == 0) ? xsrc[gidx] : agent_load(&xsrc[gidx]);
            else            val = agent_load(&hsrc[gidx - 512]);
            vlds[sel][(gidx >> 4) * 17 + (gidx & 15)] = val;
          }
        }
      }
    }
    __syncthreads();            // B: vlds ready

    // ---- 20 row dots per wave (12 VGPR rows + 8 LDS rows) ----
    {
      int curl = -1;
      u32 vreg[16];
#pragma unroll
      for (int i = 0; i < RPW; ++i) {
        int rr = wv * RPW + i;
        int p = rr >> 2;
        int g = wg * PAIRS + p;
        int lg = g >> 10;
        int t = s - lg;
        if (t >= 0 && t < SEQ) {
          if (lg != curl) {
            curl = lg;
            const u32* vb = &vlds[lg - l_lo][lane * 17];
#pragma unroll
            for (int d = 0; d < 16; ++d) vreg[d] = vb[d];
          }
          float a0 = 0.f, a1 = 0.f, a2 = 0.f, a3 = 0.f;
          if (i < NVR) {
            if (ud2) {
#pragma unroll
              for (int d = 0; d < 16; d += 4) {
                a0 = hwdot2(W[i][d],   vreg[d],   a0);
                a1 = hwdot2(W[i][d+1], vreg[d+1], a1);
                a2 = hwdot2(W[i][d+2], vreg[d+2], a2);
                a3 = hwdot2(W[i][d+3], vreg[d+3], a3);
              }
            } else {
#pragma unroll
              for (int d = 0; d < 16; d += 4) {
                a0 = fmaf(bflo(W[i][d]),   bflo(vreg[d]),   a0);
                a0 = fmaf(bfhi(W[i][d]),   bfhi(vreg[d]),   a0);
                a1 = fmaf(bflo(W[i][d+1]), bflo(vreg[d+1]), a1);
                a1 = fmaf(bfhi(W[i][d+1]), bfhi(vreg[d+1]), a1);
                a2 = fmaf(bflo(W[i][d+2]), bflo(vreg[d+2]), a2);
                a2 = fmaf(bfhi(W[i][d+2]), bfhi(vreg[d+2]), a2);
                a3 = fmaf(bflo(W[i][d+3]), bflo(vreg[d+3]), a3);
                a3 = fmaf(bfhi(W[i][d+3]), bfhi(vreg[d+3]), a3);
              }
            }
          } else {
            const uint4* wl = (const uint4*)&wlds[(wv * NLR + (i - NVR)) * 1024 + lane * 4];
#pragma unroll
            for (int d4 = 0; d4 < 4; ++d4) {
              uint4 w4 = wl[d4 * 64];
              if (ud2) {
                a0 = hwdot2(w4.x, vreg[d4*4+0], a0);
                a1 = hwdot2(w4.y, vreg[d4*4+1], a1);
                a2 = hwdot2(w4.z, vreg[d4*4+2], a2);
                a3 = hwdot2(w4.w, vreg[d4*4+3], a3);
              } else {
                a0 = fmaf(bflo(w4.x), bflo(vreg[d4*4+0]), a0);
                a0 = fmaf(bfhi(w4.x), bfhi(vreg[d4*4+0]), a0);
                a1 = fmaf(bflo(w4.y), bflo(vreg[d4*4+1]), a1);
                a1 = fmaf(bfhi(w4.y), bfhi(vreg[d4*4+1]), a1);
                a2 = fmaf(bflo(w4.z), bflo(vreg[d4*4+2]), a2);
                a2 = fmaf(bfhi(w4.z), bfhi(vreg[d4*4+2]), a2);
                a3 = fmaf(bflo(w4.w), bflo(vreg[d4*4+3]), a3);
                a3 = fmaf(bfhi(w4.w), bfhi(vreg[d4*4+3]), a3);
              }
            }
          }
          float r = (a0 + a1) + (a2 + a3);
          r += __shfl_xor(r, 32);
          r += __shfl_xor(r, 16);
          r += __shfl_xor(r, 8);
          r += __shfl_xor(r, 4);
          r += __shfl_xor(r, 2);
          r += __shfl_xor(r, 1);
          if (lane == 0) zrow[rr] = r;
        }
      }
    }
    __syncthreads();            // C: zrow ready

    // ---- wave0: gates + cell update + publish + flags ----
    if (wv == 0) {
      u16 hb = 0;
      int g = wg * PAIRS + lane;     // valid for lane < PAIRS
      int lg = g >> 10;
      int t = s - lg;
      bool act = (lane < PAIRS) && (t >= 0) && (t < SEQ);
      if (act) {
        float zi = zrow[lane * 4 + 0] + b0;
        float zf = zrow[lane * 4 + 1] + b1g;
        float zg = zrow[lane * 4 + 2] + b2g;
        float zo = zrow[lane * 4 + 3] + b3g;
        float ig = sigm(zi), fg = sigm(zf), gg = tanh_f(zg), og = sigm(zo);
        float c = fg * cst + ig * gg;
        cst = c;
        hb = f2bf(og * tanh_f(c));
      }
      u16 hnb = (u16)__shfl_xor((int)hb, 1);
      if (act && ((lane & 1) == 0)) {
        int j = g & 1023;
        u32 v = (u32)hb | ((u32)hnb << 16);
        agent_store(&slots[(size_t)(lg * RING + (t & 7)) * 512 + (j >> 1)], v);
        if (lg == NL - 1) H5[(size_t)t * 512 + (j >> 1)] = v;
      }
      rel_drain();                               // prior sc1 stores at LLC; no L2 wb/inv
      if (lane == 0) {                           // step s complete: flag = s+2
        agent_store(&flags[l_lo * 64 + (wg - f_lo)], (u32)(s + 2));
        if (l_hi != l_lo) agent_store(&flags[l_hi * 64 + (wg - f_hi)], (u32)(s + 2));
      }
    }
  }
}

// ---------------- K3: out = tanh(leaky_relu(h5) @ w2.T + b2) ----------------
__global__ void __launch_bounds__(256) k_out(const u32* __restrict__ H5,
                                             const void* __restrict__ w2,
                                             const void* __restrict__ b2,
                                             void* __restrict__ out,
                                             const u32* __restrict__ flagp) {
  const u32 isf = *flagp & 1u;
  int t = blockIdx.x, tid = threadIdx.x;
  __shared__ float hs[1024];
  __shared__ float part[256];
#pragma unroll
  for (int r = 0; r < 2; ++r) {
    int idx = tid + r * 256;
    u32 v = H5[(size_t)t * 512 + idx];
    hs[2 * idx]     = lrelu(bflo(v));
    hs[2 * idx + 1] = lrelu(bfhi(v));
  }
  __syncthreads();
  int n = tid & 63, qq = tid >> 6;
  float a = 0.f;
  if (isf) {
    const float* wr = (const float*)w2 + (size_t)n * 1024 + qq * 256;
    const float* hb = &hs[qq * 256];
#pragma unroll
    for (int d = 0; d < 256; ++d) a = fmaf(wr[d], hb[d], a);
  } else {
    const u32* wr = (const u32*)w2 + (size_t)n * 512 + qq * 128;
    const float* hb = &hs[qq * 256];
#pragma unroll
    for (int d = 0; d < 128; ++d) {
      u32 w = wr[d];
      a = fmaf(bflo(w), hb[2 * d], a);
      a = fmaf(bfhi(w), hb[2 * d + 1], a);
    }
  }
  part[tid] = a;
  __syncthreads();
  if (tid < 64) {
    float bb = isf ? ((const float*)b2)[tid] : bf2f(((const u16*)b2)[tid]);
    float y = part[tid] + part[tid + 64] + part[tid + 128] + part[tid + 192] + bb;
    float r = tanh_f(y);
    if (isf) ((float*)out)[(size_t)t * 64 + tid] = r;
    else     ((u16*)out)[(size_t)t * 64 + tid] = f2bf(r);
  }
}

// ---------------- launcher ----------------
extern "C" void kernel_launch(void* const* d_in, const int* in_sizes, int n_in,
                              void* d_out, int out_size, void* d_ws, size_t ws_size,
                              hipStream_t stream) {
  (void)in_sizes; (void)n_in; (void)out_size;
  if (ws_size < WS_NEED) return;

  const void* din = d_in[0];
  const void* w1  = d_in[1];
  const void* b1  = d_in[2];
  const void* Wih = d_in[3];
  const void* Whh = d_in[4];
  const void* bih = d_in[5];
  const void* bhh = d_in[6];
  const void* w2  = d_in[7];
  const void* b2  = d_in[8];
  const void* h0  = d_in[9];
  const void* c0  = d_in[10];

  char* ws = (char*)d_ws;
  u32* X0    = (u32*)(ws + WS_X0);
  u32* H5    = (u32*)(ws + WS_H5);
  u32* slot  = (u32*)(ws + WS_SLOT);
  u32* flags = (u32*)(ws + WS_SYNC);
  u32* dflag = (u32*)(ws + WS_SYNC + 2048);

  hipMemsetAsync(flags, 0, 4096, stream);      // zero flags + dtype word (ws poisoned 0xAA)
  k_detect<<<1, 64, 0, stream>>>((const u32*)w1, dflag);
  k_in  <<<SEQ, 256, 0, stream>>>(din, w1, b1, X0, dflag);
  k_wave<<<NWG, TPB, 0, stream>>>(Wih, Whh, bih, bhh, h0, c0, X0, H5, slot, flags, dflag);
  k_out <<<SEQ, 256, 0, stream>>>(H5, w2, b2, d_out, dflag);
}

// Round 4
// 103645.496 us; speedup vs baseline: 1.2250x; 1.1613x over previous
//
#include <hip/hip_runtime.h>
#include <stdint.h>

typedef unsigned int  u32;
typedef unsigned short u16;
typedef unsigned long long u64;

#define SEQ    8192
#define HID    1024
#define NL     5
#define NWG    256
#define TPB    256
#define PAIRS  20                 // (layer,unit) pairs per WG; NWG*PAIRS = NL*HID
#define RPW    20                 // gate-rows per wave (4 waves * 20 = 80 = PAIRS*4)
#define NVR    12                 // rows kept in VGPRs per wave
#define NLR    8                  // rows kept in LDS per wave (NVR+NLR == RPW)
#define WSTEPS (SEQ + NL - 1)     // 8196 wavefront steps
#define LWGS   52                 // producer WGs per layer
#define RING   16                 // slot ring depth (WAR slack = RING-2 = 14 steps)

// ---- workspace layout (bytes) ----
#define WS_X0    ((size_t)0)                        // 8192*512 u32 = 16 MiB (bf16 packed)
#define WS_H5    ((size_t)16*1024*1024)             // 16 MiB
#define WS_SLOT  ((size_t)32*1024*1024)             // 5*16*512 u64 = 320 KiB (pad 384 KiB)
#define WS_SYNC  (WS_SLOT + (size_t)384*1024)       // epochs[5] (128-B spaced); dtype flag @+2048
#define WS_NEED  (WS_SYNC + 4096)

// ---------------- helpers ----------------
__device__ __forceinline__ float bf2f(u16 v) { return __uint_as_float(((u32)v) << 16); }
__device__ __forceinline__ float bflo(u32 v) { return __uint_as_float(v << 16); }
__device__ __forceinline__ float bfhi(u32 v) { return __uint_as_float(v & 0xffff0000u); }

__device__ __forceinline__ u16 f2bf(float f) {            // round-to-nearest-even
  u32 u = __float_as_uint(f);
  u32 r = u + 0x7fffu + ((u >> 16) & 1u);
  return (u16)(r >> 16);
}
__device__ __forceinline__ float lrelu(float x) { return (x >= 0.f) ? x : 0.01f * x; }
__device__ __forceinline__ float sigm(float x)  { return 1.f / (1.f + __expf(-x)); }
__device__ __forceinline__ float tanh_f(float x) {
  float e = __expf(-2.f * fabsf(x));
  float t = (1.f - e) / (1.f + e);
  return (x >= 0.f) ? t : -t;
}

// software packed-bf16x2 dot (bit-exact unpack + f32 fma) — proven fallback
__device__ __forceinline__ float dot2bf(u32 w, u32 v, float acc) {
  return fmaf(bfhi(w), bfhi(v), fmaf(bflo(w), bflo(v), acc));
}

// hardware v_dot2_f32_bf16 — validated at runtime by k_detect before use
#if defined(__has_builtin)
#if __has_builtin(__builtin_amdgcn_fdot2_f32_bf16)
#define HAS_DOT2 1
typedef __bf16 bf16x2 __attribute__((ext_vector_type(2)));
__device__ __forceinline__ float hwdot2(u32 a, u32 b, float c) {
  union U { u32 u; bf16x2 v; };
  U x, y; x.u = a; y.u = b;
  return __builtin_amdgcn_fdot2_f32_bf16(x.v, y.v, c, false);
}
#endif
#endif
#ifndef HAS_DOT2
#define HAS_DOT2 0
__device__ __forceinline__ float hwdot2(u32 a, u32 b, float c) { return dot2bf(a, b, c); }
#endif

__device__ __forceinline__ u32 agent_load(const u32* p) {
  return __hip_atomic_load((u32*)p, __ATOMIC_RELAXED, __HIP_MEMORY_SCOPE_AGENT);
}
// 8-B LLC-coherent slot ops. A naturally-aligned 8-B store/load is one memory
// transaction, so tag (hi word) and data (lo word) are read/written together:
// tag == expected  =>  data word is the matching step's value. This IS the sync.
__device__ __forceinline__ u64 slot_load(const u64* p) {
  return __hip_atomic_load((u64*)p, __ATOMIC_RELAXED, __HIP_MEMORY_SCOPE_AGENT);
}
__device__ __forceinline__ void slot_store(u64* p, u64 v) {
  __hip_atomic_store(p, v, __ATOMIC_RELAXED, __HIP_MEMORY_SCOPE_AGENT);
}
__device__ __forceinline__ void epoch_add(u32* p) {
  (void)__hip_atomic_fetch_add(p, 1u, __ATOMIC_RELAXED, __HIP_MEMORY_SCOPE_AGENT);
}

// ---------------- K0: dtype probe + dot2 validation ----------------
__global__ void k_detect(const u32* __restrict__ w1, u32* __restrict__ flag) {
  int lane = threadIdx.x;       // 64 threads
  int cnt = 0;
#pragma unroll
  for (int i = 0; i < 4; ++i) {
    u32 w = w1[lane * 4 + i];
    u32 e = (w >> 23) & 0xffu;
    cnt += (e >= 100u && e <= 140u) ? 1 : 0;
  }
  cnt += __shfl_xor(cnt, 32); cnt += __shfl_xor(cnt, 16); cnt += __shfl_xor(cnt, 8);
  cnt += __shfl_xor(cnt, 4);  cnt += __shfl_xor(cnt, 2);  cnt += __shfl_xor(cnt, 1);
  if (lane == 0) {
    u32 f = (cnt > 128) ? 1u : 0u;
#if HAS_DOT2
    u32 a1 = (u32)f2bf(1.5f)   | ((u32)f2bf(-2.25f) << 16);
    u32 b1v = (u32)f2bf(0.5f)  | ((u32)f2bf(4.0f)   << 16);
    u32 a2 = (u32)f2bf(0.125f) | ((u32)f2bf(3.0f)   << 16);
    u32 b2v = (u32)f2bf(8.0f)  | ((u32)f2bf(-0.5f)  << 16);
    float t1 = hwdot2(a1, b1v, 1.0f);   // 1 + 0.75 - 9   = -7.25
    float t2 = hwdot2(a2, b2v, 0.5f);   // 0.5 + 1 - 1.5  = 0
    if (fabsf(t1 + 7.25f) < 1e-2f && fabsf(t2) < 1e-2f) f |= 2u;
#endif
    *flag = f;
  }
}

// ---------------- K1: X0 = leaky_relu(data_in @ w1.T + b1), stored packed bf16 ----------------
__global__ void __launch_bounds__(256) k_in(const void* __restrict__ din,
                                            const void* __restrict__ w1,
                                            const void* __restrict__ b1,
                                            u32* __restrict__ X0,
                                            const u32* __restrict__ flagp) {
  const u32 isf = *flagp & 1u;
  int t = blockIdx.x, tid = threadIdx.x;
  __shared__ float xs[64];
  if (isf) {
    if (tid < 64) xs[tid] = ((const float*)din)[(size_t)t * 64 + tid];
  } else {
    if (tid < 32) {
      u32 v = ((const u32*)din)[(size_t)t * 32 + tid];
      xs[2 * tid] = bflo(v); xs[2 * tid + 1] = bfhi(v);
    }
  }
  __syncthreads();
  float o[4];
#pragma unroll
  for (int r = 0; r < 4; ++r) {
    int i = tid * 4 + r;
    float a = 0.f;
    if (isf) {
      const float* wr = (const float*)w1 + (size_t)i * 64;
#pragma unroll
      for (int d = 0; d < 64; ++d) a = fmaf(wr[d], xs[d], a);
      a += ((const float*)b1)[i];
    } else {
      const u32* wr = (const u32*)w1 + (size_t)i * 32;
#pragma unroll
      for (int d = 0; d < 32; ++d) {
        u32 w = wr[d];
        a = fmaf(bflo(w), xs[2 * d], a);
        a = fmaf(bfhi(w), xs[2 * d + 1], a);
      }
      a += bf2f(((const u16*)b1)[i]);
    }
    o[r] = lrelu(a);
  }
  X0[(size_t)t * 512 + tid * 2]     = (u32)f2bf(o[0]) | ((u32)f2bf(o[1]) << 16);
  X0[(size_t)t * 512 + tid * 2 + 1] = (u32)f2bf(o[2]) | ((u32)f2bf(o[3]) << 16);
}

// ---------------- K2: persistent wavefront LSTM — tag-in-data push protocol ----------------
// Slot = u64 per h-pair: [tag=t (hi) | bf16x2 pair (lo)], slots[l][t&15][512].
// Publish: one 8-B fire-and-forget LLC store per pair (no drain, no flags).
// Consume: the staging load compares the tag word inline and retries only
// stale words — detection and data transfer are THE SAME memory operation.
// Ring aliasing: impossible (tag is the exact 32-bit t; slots memset 0xAA
// per launch kills cross-run aliasing). WAR (slot reuse after RING steps,
// slack = RING-2 = 14): per-layer epoch counters (relaxed atomicAdd, one per
// WG per owned layer per step); producers check epoch[l+1] >= 52*(s-14) before
// overwriting — with 14-step slack this is almost never binding.
// All spins share ONE global budget -> kernel is provably terminating.
__global__ void __launch_bounds__(TPB, 1) k_wave(const void* __restrict__ WihP,
                                                 const void* __restrict__ WhhP,
                                                 const void* __restrict__ bihP,
                                                 const void* __restrict__ bhhP,
                                                 const void* __restrict__ h0P,
                                                 const void* __restrict__ c0P,
                                                 const u32* __restrict__ X0,
                                                 u32* __restrict__ H5,
                                                 u64* slots64, u32* epochs,
                                                 const u32* __restrict__ flagp) {
  const u32 dfl = *flagp;
  const u32 isf = dfl & 1u;
  const bool ud2 = (dfl & 2u) != 0u;
  const int tid  = threadIdx.x;
  const int lane = tid & 63;
  const int wv   = tid >> 6;
  const int wg   = blockIdx.x;

  __shared__ u32   vlds[2][64 * 17];            // [layer-sel][lane*17 + d] (odd stride: conflict-free)
  __shared__ u32   wlds[4 * NLR * 1024];        // [wave][row][d4][lane][4] 128 KiB, b128-friendly
  __shared__ float zrow[80];

  // ---- load weights: rows 0..NVR-1 -> VGPRs, rows NVR..19 -> LDS ----
  u32 W[NVR][16];
#pragma unroll
  for (int i = 0; i < RPW; ++i) {
    int rr = wv * RPW + i;
    int p = rr >> 2, q = rr & 3;
    int g = wg * PAIRS + p;
    int lg = g >> 10, j = g & 1023;
    u32 tmp[16];
    if (isf) {
      const float* matf = (lane < 32) ? (const float*)WihP : (const float*)WhhP;
      const float4* s4 = (const float4*)(matf + ((size_t)(lg * 4096 + q * 1024 + j)) * 1024 + (lane & 31) * 32);
#pragma unroll
      for (int q4 = 0; q4 < 8; ++q4) {
        float4 f = s4[q4];
        tmp[q4 * 2]     = (u32)f2bf(f.x) | ((u32)f2bf(f.y) << 16);
        tmp[q4 * 2 + 1] = (u32)f2bf(f.z) | ((u32)f2bf(f.w) << 16);
      }
    } else {
      const u32* mat = (lane < 32) ? (const u32*)WihP : (const u32*)WhhP;
      const uint4* s4 = (const uint4*)(mat + ((size_t)(lg * 4096 + q * 1024 + j)) * 512 + (lane & 31) * 16);
      uint4 a0 = s4[0], a1 = s4[1], a2 = s4[2], a3 = s4[3];
      tmp[0]=a0.x; tmp[1]=a0.y; tmp[2]=a0.z;  tmp[3]=a0.w;
      tmp[4]=a1.x; tmp[5]=a1.y; tmp[6]=a1.z;  tmp[7]=a1.w;
      tmp[8]=a2.x; tmp[9]=a2.y; tmp[10]=a2.z; tmp[11]=a2.w;
      tmp[12]=a3.x;tmp[13]=a3.y;tmp[14]=a3.z; tmp[15]=a3.w;
    }
    if (i < NVR) {
#pragma unroll
      for (int d = 0; d < 16; ++d) W[i][d] = tmp[d];
    } else {
      u32* base = &wlds[(wv * NLR + (i - NVR)) * 1024];
#pragma unroll
      for (int d4 = 0; d4 < 4; ++d4) {
        uint4 v4 = make_uint4(tmp[d4*4], tmp[d4*4+1], tmp[d4*4+2], tmp[d4*4+3]);
        *(uint4*)&base[d4 * 256 + lane * 4] = v4;
      }
    }
  }

  // ---- per-unit state in wave0 registers (lane < PAIRS owns one unit) ----
  float cst = 0.f;
  float b0 = 0.f, b1g = 0.f, b2g = 0.f, b3g = 0.f;
  if (wv == 0 && lane < PAIRS) {
    int g = wg * PAIRS + lane, lg = g >> 10, j = g & 1023;
    cst = isf ? ((const float*)c0P)[lg * 1024 + j] : bf2f(((const u16*)c0P)[lg * 1024 + j]);
#pragma unroll
    for (int q = 0; q < 4; ++q) {
      int r = lg * 4096 + q * 1024 + j;
      float bb = isf ? (((const float*)bihP)[r] + ((const float*)bhhP)[r])
                     : (bf2f(((const u16*)bihP)[r]) + bf2f(((const u16*)bhhP)[r]));
      if (q == 0) b0 = bb; else if (q == 1) b1g = bb; else if (q == 2) b2g = bb; else b3g = bb;
    }
  }
  if (tid < PAIRS / 2) {          // h0 -> ring slot RING-1 (t = -1), tag = 0xFFFFFFFF
    int g = wg * PAIRS + 2 * tid, lg = g >> 10, j = g & 1023;
    u32 v;
    if (isf) {
      const float* h0f = (const float*)h0P;
      v = (u32)f2bf(h0f[lg * 1024 + j]) | ((u32)f2bf(h0f[lg * 1024 + j + 1]) << 16);
    } else {
      const u16* h0b = (const u16*)h0P;
      v = (u32)h0b[lg * 1024 + j] | ((u32)h0b[lg * 1024 + j + 1] << 16);
    }
    slot_store(&slots64[(size_t)(lg * RING + (RING - 1)) * 512 + (j >> 1)],
               ((u64)0xFFFFFFFFull << 32) | (u64)v);
  }
  // no init fence/flag needed: tags self-synchronize (stale tag => retry)

  const int l_lo = (wg * PAIRS) >> 10;
  const int l_hi = (wg * PAIRS + PAIRS - 1) >> 10;

  int budget = 20000000;                        // bounded polling: never hard-hang

  for (int s = 0; s < WSTEPS; ++s) {
    // ---- stage v = [x || h] per owned layer; tag match inline (THE sync) ----
#pragma unroll
    for (int sel = 0; sel < 2; ++sel) {
      int L = l_lo + sel;
      if (L <= l_hi) {
        int t = s - L;
        if (t >= 0 && t < SEQ) {
          const u64* hsrc = slots64 + (size_t)(L * RING + ((t - 1) & (RING - 1))) * 512;
          const u64* xsrc = (L > 0) ? slots64 + (size_t)((L - 1) * RING + (t & (RING - 1))) * 512
                                    : (const u64*)0;
          const u32 exph = (u32)(t - 1);        // t=0 -> 0xFFFFFFFF (h0 tag)
          const u32 expx = (u32)t;
          u32 okm = 0;
          u32 dat[4] = {0u, 0u, 0u, 0u};        // defined even on budget exhaust
          int miss = 0;
          for (;;) {
#pragma unroll
            for (int rr2 = 0; rr2 < 4; ++rr2) {
              if (!(okm & (1u << rr2))) {
                int gidx = tid + rr2 * 256;
                if (gidx < 512) {               // x pair
                  if (L == 0) { dat[rr2] = X0[(size_t)t * 512 + gidx]; okm |= 1u << rr2; }
                  else {
                    u64 v = slot_load(xsrc + gidx);
                    if ((u32)(v >> 32) == expx) { dat[rr2] = (u32)v; okm |= 1u << rr2; }
                  }
                } else {                         // h pair
                  u64 v = slot_load(hsrc + (gidx - 512));
                  if ((u32)(v >> 32) == exph) { dat[rr2] = (u32)v; okm |= 1u << rr2; }
                }
              }
            }
            if (__all(okm == 15u)) break;
            if (--budget < 0) break;
            if (++miss >= 16) __builtin_amdgcn_s_sleep(1);   // stragglers only
          }
#pragma unroll
          for (int rr2 = 0; rr2 < 4; ++rr2) {
            int gidx = tid + rr2 * 256;
            vlds[sel][(gidx >> 4) * 17 + (gidx & 15)] = dat[rr2];
          }
        }
      }
    }
    __syncthreads();            // B: vlds ready

    // ---- 20 row dots per wave (12 VGPR rows + 8 LDS rows) ----
    {
      int curl = -1;
      u32 vreg[16];
#pragma unroll
      for (int i = 0; i < RPW; ++i) {
        int rr = wv * RPW + i;
        int p = rr >> 2;
        int g = wg * PAIRS + p;
        int lg = g >> 10;
        int t = s - lg;
        if (t >= 0 && t < SEQ) {
          if (lg != curl) {
            curl = lg;
            const u32* vb = &vlds[lg - l_lo][lane * 17];
#pragma unroll
            for (int d = 0; d < 16; ++d) vreg[d] = vb[d];
          }
          float a0 = 0.f, a1 = 0.f, a2 = 0.f, a3 = 0.f;
          if (i < NVR) {
            if (ud2) {
#pragma unroll
              for (int d = 0; d < 16; d += 4) {
                a0 = hwdot2(W[i][d],   vreg[d],   a0);
                a1 = hwdot2(W[i][d+1], vreg[d+1], a1);
                a2 = hwdot2(W[i][d+2], vreg[d+2], a2);
                a3 = hwdot2(W[i][d+3], vreg[d+3], a3);
              }
            } else {
#pragma unroll
              for (int d = 0; d < 16; d += 4) {
                a0 = fmaf(bflo(W[i][d]),   bflo(vreg[d]),   a0);
                a0 = fmaf(bfhi(W[i][d]),   bfhi(vreg[d]),   a0);
                a1 = fmaf(bflo(W[i][d+1]), bflo(vreg[d+1]), a1);
                a1 = fmaf(bfhi(W[i][d+1]), bfhi(vreg[d+1]), a1);
                a2 = fmaf(bflo(W[i][d+2]), bflo(vreg[d+2]), a2);
                a2 = fmaf(bfhi(W[i][d+2]), bfhi(vreg[d+2]), a2);
                a3 = fmaf(bflo(W[i][d+3]), bflo(vreg[d+3]), a3);
                a3 = fmaf(bfhi(W[i][d+3]), bfhi(vreg[d+3]), a3);
              }
            }
          } else {
            const uint4* wl = (const uint4*)&wlds[(wv * NLR + (i - NVR)) * 1024 + lane * 4];
#pragma unroll
            for (int d4 = 0; d4 < 4; ++d4) {
              uint4 w4 = wl[d4 * 64];
              if (ud2) {
                a0 = hwdot2(w4.x, vreg[d4*4+0], a0);
                a1 = hwdot2(w4.y, vreg[d4*4+1], a1);
                a2 = hwdot2(w4.z, vreg[d4*4+2], a2);
                a3 = hwdot2(w4.w, vreg[d4*4+3], a3);
              } else {
                a0 = fmaf(bflo(w4.x), bflo(vreg[d4*4+0]), a0);
                a0 = fmaf(bfhi(w4.x), bfhi(vreg[d4*4+0]), a0);
                a1 = fmaf(bflo(w4.y), bflo(vreg[d4*4+1]), a1);
                a1 = fmaf(bfhi(w4.y), bfhi(vreg[d4*4+1]), a1);
                a2 = fmaf(bflo(w4.z), bflo(vreg[d4*4+2]), a2);
                a2 = fmaf(bfhi(w4.z), bfhi(vreg[d4*4+2]), a2);
                a3 = fmaf(bflo(w4.w), bflo(vreg[d4*4+3]), a3);
                a3 = fmaf(bfhi(w4.w), bfhi(vreg[d4*4+3]), a3);
              }
            }
          }
          float r = (a0 + a1) + (a2 + a3);
          r += __shfl_xor(r, 32);
          r += __shfl_xor(r, 16);
          r += __shfl_xor(r, 8);
          r += __shfl_xor(r, 4);
          r += __shfl_xor(r, 2);
          r += __shfl_xor(r, 1);
          if (lane == 0) zrow[rr] = r;
        }
      }
    }
    __syncthreads();            // C: zrow ready

    // ---- wave0: WAR guard + gates + cell update + tagged publish + epochs ----
    if (wv == 0) {
      // WAR: before overwriting slot (t & 15) (previous content t-16), make sure
      // layer L+1 finished step s-15 (i.e. epoch[L+1] >= 52*(s-14)). 14-step
      // slack => almost never spins. Same-address load from all lanes = 1 req.
      if (s >= RING - 1) {
        u32 needw = 52u * (u32)(s - (RING - 2));
#pragma unroll
        for (int sel = 0; sel < 2; ++sel) {
          int L = l_lo + sel;
          if (L <= l_hi && (L + 1) < NL) {
            int tL = s - L;
            if (tL >= 0 && tL < SEQ) {
              while (agent_load(&epochs[(L + 1) * 32]) < needw) {
                if (--budget < 0) break;
                __builtin_amdgcn_s_sleep(4);
              }
            }
          }
        }
      }
      u16 hb = 0;
      int g = wg * PAIRS + lane;     // valid for lane < PAIRS
      int lg = g >> 10;
      int t = s - lg;
      bool act = (lane < PAIRS) && (t >= 0) && (t < SEQ);
      if (act) {
        float zi = zrow[lane * 4 + 0] + b0;
        float zf = zrow[lane * 4 + 1] + b1g;
        float zg = zrow[lane * 4 + 2] + b2g;
        float zo = zrow[lane * 4 + 3] + b3g;
        float ig = sigm(zi), fg = sigm(zf), gg = tanh_f(zg), og = sigm(zo);
        float c = fg * cst + ig * gg;
        cst = c;
        hb = f2bf(og * tanh_f(c));
      }
      u16 hnb = (u16)__shfl_xor((int)hb, 1);
      if (act && ((lane & 1) == 0)) {
        int j = g & 1023;
        u32 v = (u32)hb | ((u32)hnb << 16);
        slot_store(&slots64[(size_t)(lg * RING + (t & (RING - 1))) * 512 + (j >> 1)],
                   ((u64)(u32)t << 32) | (u64)v);      // fire-and-forget
        if (lg == NL - 1) H5[(size_t)t * 512 + (j >> 1)] = v;
      }
      if (lane == 0) {               // step s complete for owned layers
        epoch_add(&epochs[l_lo * 32]);
        if (l_hi != l_lo) epoch_add(&epochs[l_hi * 32]);
      }
    }
  }
}

// ---------------- K3: out = tanh(leaky_relu(h5) @ w2.T + b2) ----------------
__global__ void __launch_bounds__(256) k_out(const u32* __restrict__ H5,
                                             const void* __restrict__ w2,
                                             const void* __restrict__ b2,
                                             void* __restrict__ out,
                                             const u32* __restrict__ flagp) {
  const u32 isf = *flagp & 1u;
  int t = blockIdx.x, tid = threadIdx.x;
  __shared__ float hs[1024];
  __shared__ float part[256];
#pragma unroll
  for (int r = 0; r < 2; ++r) {
    int idx = tid + r * 256;
    u32 v = H5[(size_t)t * 512 + idx];
    hs[2 * idx]     = lrelu(bflo(v));
    hs[2 * idx + 1] = lrelu(bfhi(v));
  }
  __syncthreads();
  int n = tid & 63, qq = tid >> 6;
  float a = 0.f;
  if (isf) {
    const float* wr = (const float*)w2 + (size_t)n * 1024 + qq * 256;
    const float* hb = &hs[qq * 256];
#pragma unroll
    for (int d = 0; d < 256; ++d) a = fmaf(wr[d], hb[d], a);
  } else {
    const u32* wr = (const u32*)w2 + (size_t)n * 512 + qq * 128;
    const float* hb = &hs[qq * 256];
#pragma unroll
    for (int d = 0; d < 128; ++d) {
      u32 w = wr[d];
      a = fmaf(bflo(w), hb[2 * d], a);
      a = fmaf(bfhi(w), hb[2 * d + 1], a);
    }
  }
  part[tid] = a;
  __syncthreads();
  if (tid < 64) {
    float bb = isf ? ((const float*)b2)[tid] : bf2f(((const u16*)b2)[tid]);
    float y = part[tid] + part[tid + 64] + part[tid + 128] + part[tid + 192] + bb;
    float r = tanh_f(y);
    if (isf) ((float*)out)[(size_t)t * 64 + tid] = r;
    else     ((u16*)out)[(size_t)t * 64 + tid] = f2bf(r);
  }
}

// ---------------- launcher ----------------
extern "C" void kernel_launch(void* const* d_in, const int* in_sizes, int n_in,
                              void* d_out, int out_size, void* d_ws, size_t ws_size,
                              hipStream_t stream) {
  (void)in_sizes; (void)n_in; (void)out_size;
  if (ws_size < WS_NEED) return;

  const void* din = d_in[0];
  const void* w1  = d_in[1];
  const void* b1  = d_in[2];
  const void* Wih = d_in[3];
  const void* Whh = d_in[4];
  const void* bih = d_in[5];
  const void* bhh = d_in[6];
  const void* w2  = d_in[7];
  const void* b2  = d_in[8];
  const void* h0  = d_in[9];
  const void* c0  = d_in[10];

  char* ws = (char*)d_ws;
  u32* X0     = (u32*)(ws + WS_X0);
  u32* H5     = (u32*)(ws + WS_H5);
  u64* slot   = (u64*)(ws + WS_SLOT);
  u32* epochs = (u32*)(ws + WS_SYNC);
  u32* dflag  = (u32*)(ws + WS_SYNC + 2048);

  // slot tags must not alias any valid tag (t in [0,SEQ) or 0xFFFFFFFF):
  // 0xAAAAAAAA is neither. memset per launch kills cross-run tag aliasing.
  hipMemsetAsync(slot, 0xAA, (size_t)NL * RING * 512 * 8, stream);
  hipMemsetAsync(epochs, 0, 4096, stream);     // epochs + dtype word
  k_detect<<<1, 64, 0, stream>>>((const u32*)w1, dflag);
  k_in  <<<SEQ, 256, 0, stream>>>(din, w1, b1, X0, dflag);
  k_wave<<<NWG, TPB, 0, stream>>>(Wih, Whh, bih, bhh, h0, c0, X0, H5, slot, epochs, dflag);
  k_out <<<SEQ, 256, 0, stream>>>(H5, w2, b2, d_out, dflag);
}